// Round 14
// baseline (126.384 us; speedup 1.0000x reference)
//
#include <hip/hip_runtime.h>
#include <math.h>

#define B_   2
#define NQ_  10000
#define NV_  21760
#define EMB  256
#define MQ   (B_*NQ_)   // 20000
#define MV   (B_*NV_)   // 43520

typedef short bf16x8 __attribute__((ext_vector_type(8)));
typedef float f32x4  __attribute__((ext_vector_type(4)));

__device__ constexpr int LSc[4] = {0, 16384, 20480, 21504};

__device__ __forceinline__ unsigned short f2bf(float x) {
  unsigned u = __builtin_bit_cast(unsigned, x);
  u += 0x7FFFu + ((u >> 16) & 1u);
  return (unsigned short)(u >> 16);
}
__device__ __forceinline__ float bf2f(unsigned short s) {
  return __builtin_bit_cast(float, (unsigned)s << 16);
}

// ---------------------------------------------------------------------------
// Weight prep (unchanged).
// ---------------------------------------------------------------------------
__global__ __launch_bounds__(256) void prep_weights(
    const float* __restrict__ Wv, const float* __restrict__ Wattn,
    const float* __restrict__ Woff, const float* __restrict__ Wout,
    unsigned short* __restrict__ WvT, unsigned short* __restrict__ WoutT,
    unsigned short* __restrict__ WqHi, unsigned short* __restrict__ WqLo) {
  int n = blockIdx.x;       // 0..895
  int k = threadIdx.x;      // 0..255
  if (n < 256) {
    WvT[n * 256 + k] = f2bf(Wv[k * 256 + n]);
  } else if (n < 512) {
    int c = n - 256;
    WoutT[c * 256 + k] = f2bf(Wout[k * 256 + c]);
  } else {
    int qr = n - 512;       // 0..383
    float x = (qr < 256) ? Woff[k * 256 + qr] : Wattn[k * 128 + (qr - 256)];
    unsigned short hi = f2bf(x);
    WqHi[qr * 256 + k] = hi;
    WqLo[qr * 256 + k] = f2bf(x - bf2f(hi));
  }
}

// ---------------------------------------------------------------------------
// query -> q_hi (bf16) + q_lo (bf16 residual), once. (R5's split_query.)
// ---------------------------------------------------------------------------
__global__ __launch_bounds__(256) void split_query(
    const float4* __restrict__ q, ushort4* __restrict__ qhi,
    ushort4* __restrict__ qlo) {
  int i = blockIdx.x * 256 + threadIdx.x;
  float4 v = q[i];
  ushort4 h, l;
  h.x = f2bf(v.x); l.x = f2bf(v.x - bf2f(h.x));
  h.y = f2bf(v.y); l.y = f2bf(v.y - bf2f(h.y));
  h.z = f2bf(v.z); l.z = f2bf(v.z - bf2f(h.z));
  h.w = f2bf(v.w); l.w = f2bf(v.w - bf2f(h.w));
  qhi[i] = h; qlo[i] = l;
}

// ---------------------------------------------------------------------------
// MFMA GEMM. 128x128 tile, BK=32, 4 waves (2x2), 4x4 16x16x32 frags/wave.
// bf16 staging via global_load_lds(16B): linear LDS dest, pre-swizzled src.
// MODE 0: A bf16, 1-term.   MODE 1: A fp32 (cvt in staging), 1-term.
// MODE 4: A = (Aa=hi, Ab=lo) bf16, all staging via global_load_lds;
//         3-term for col0<256 (off cols), 1-term for attn cols (bf16 C2).
// VPERM:  v-proj epilogue -> pair-packed bf16 v via LDS + coalesced stores.
// ---------------------------------------------------------------------------
template <int MODE, typename OutT, bool VPERM = false>
__global__ __launch_bounds__(256) void gemm_mfma(
    const void* __restrict__ Aa, const void* __restrict__ Ab,
    const unsigned short* __restrict__ Bt, const unsigned short* __restrict__ Bt2,
    const float* __restrict__ bias, const float* __restrict__ bias2,
    OutT* __restrict__ C, unsigned short* __restrict__ C2, int M, int N) {
  constexpr int BM = 128, BK = 32;
  constexpr int SMEM_SHORTS = (MODE == 4 || VPERM) ? 16384 : 8192;
  __shared__ unsigned short smem[SMEM_SHORTS];
  unsigned short* As  = smem;
  unsigned short* Bs  = smem + ((MODE == 4) ? 2 : 1) * BM * BK;
  unsigned short* As2 = smem + BM * BK;       // MODE4 only
  unsigned short* Bs2 = smem + 3 * BM * BK;   // MODE4 only

  const int tid = threadIdx.x;
  const int lane = tid & 63, wv = tid >> 6;
  const int wr = wv >> 1, wc = wv & 1;
  const int row0 = blockIdx.x * BM, col0 = blockIdx.y * BM;

  auto lds_addr = [](int row, int kslot) -> int {
    return row * 64 + ((kslot ^ ((row >> 1) & 3)) << 4);
  };

  // bf16 staging via global_load_lds(16B): linear LDS dest, pre-swizzled src.
  auto stage_bf = [&](unsigned short* dst, const unsigned short* src,
                      int rbase, int rmax, int kk) {
#pragma unroll
    for (int i = 0; i < 2; ++i) {
      int idx = tid + 256 * i;
      int row = idx >> 2, ks = idx & 3;
      int rg = min(rbase + row, rmax);
      int xorb = (row >> 1) & 3;
      const unsigned short* gp =
          src + (size_t)rg * 256 + kk + ((ks ^ xorb) << 3);
      unsigned short* lp = dst + (size_t)(wv * 64 + i * 256) * 8;
      __builtin_amdgcn_global_load_lds(
          (const __attribute__((address_space(1))) void*)gp,
          (__attribute__((address_space(3))) void*)lp, 16, 0, 0);
    }
  };
  auto stage_cvt = [&](unsigned short* dst, const float* src,
                       int rbase, int rmax, int kk) {
#pragma unroll
    for (int i = 0; i < 4; ++i) {
      int idx = tid + 256 * i;
      int row = idx >> 3, c4 = idx & 7;
      int rg = min(rbase + row, rmax);
      float4 vdat = *(const float4*)(src + (size_t)rg * 256 + kk + c4 * 4);
      ushort4 o;
      o.x = f2bf(vdat.x); o.y = f2bf(vdat.y);
      o.z = f2bf(vdat.z); o.w = f2bf(vdat.w);
      *(ushort4*)((char*)dst + lds_addr(row, c4 >> 1) + (c4 & 1) * 8) = o;
    }
  };

  const bool three_term = (MODE == 4) && (col0 < 256);

  f32x4 acc[4][4] = {};

  for (int kk = 0; kk < 256; kk += BK) {
    if (kk) __syncthreads();
    if constexpr (MODE == 1)
      stage_cvt(As, (const float*)Aa, row0, M - 1, kk);
    else
      stage_bf(As, (const unsigned short*)Aa, row0, M - 1, kk);
    stage_bf(Bs, Bt, col0, N - 1, kk);
    if constexpr (MODE == 4) {
      if (three_term) {
        stage_bf(As2, (const unsigned short*)Ab, row0, M - 1, kk);
        stage_bf(Bs2, Bt2, col0, N - 1, kk);
      }
    }
    __syncthreads();

    const int kslot = lane >> 4;
    bf16x8 af[4], bfr[4];
#pragma unroll
    for (int i = 0; i < 4; ++i) {
      int ra = wr * 64 + i * 16 + (lane & 15);
      af[i] = *(const bf16x8*)((const char*)As + lds_addr(ra, kslot));
      int rb = wc * 64 + i * 16 + (lane & 15);
      bfr[i] = *(const bf16x8*)((const char*)Bs + lds_addr(rb, kslot));
    }
#pragma unroll
    for (int mi = 0; mi < 4; ++mi)
#pragma unroll
      for (int ni = 0; ni < 4; ++ni)
        acc[mi][ni] = __builtin_amdgcn_mfma_f32_16x16x32_bf16(
            af[mi], bfr[ni], acc[mi][ni], 0, 0, 0);

    if constexpr (MODE == 4) {
      if (three_term) {
        bf16x8 af2[4], bfr2[4];
#pragma unroll
        for (int i = 0; i < 4; ++i) {
          int ra = wr * 64 + i * 16 + (lane & 15);
          af2[i] = *(const bf16x8*)((const char*)As2 + lds_addr(ra, kslot));
          int rb = wc * 64 + i * 16 + (lane & 15);
          bfr2[i] = *(const bf16x8*)((const char*)Bs2 + lds_addr(rb, kslot));
        }
#pragma unroll
        for (int mi = 0; mi < 4; ++mi)
#pragma unroll
          for (int ni = 0; ni < 4; ++ni) {
            acc[mi][ni] = __builtin_amdgcn_mfma_f32_16x16x32_bf16(
                af2[mi], bfr[ni], acc[mi][ni], 0, 0, 0);   // lo @ hi
            acc[mi][ni] = __builtin_amdgcn_mfma_f32_16x16x32_bf16(
                af[mi], bfr2[ni], acc[mi][ni], 0, 0, 0);   // hi @ lo
          }
      }
    }
  }

  // epilogue: D frag layout col=lane&15, row=(lane>>4)*4+reg  [m89-verified]
  if constexpr (VPERM) {
    float bb4[4];
#pragma unroll
    for (int ni = 0; ni < 4; ++ni)
      bb4[ni] = bias[col0 + wc * 64 + ni * 16 + (lane & 15)];
    __syncthreads();                 // As/Bs dead; reuse the 32 KB
    unsigned short* pbuf = smem;
#pragma unroll
    for (int mi = 0; mi < 4; ++mi) {
#pragma unroll
      for (int r = 0; r < 4; ++r) {
        int lr = wr * 64 + mi * 16 + ((lane >> 4) << 2) + r;  // local row
        int pb = lr >> 1, par = lr & 1;
#pragma unroll
        for (int ni = 0; ni < 4; ++ni) {
          int lc = wc * 64 + ni * 16 + (lane & 15);
          float val = acc[mi][ni][r] + bb4[ni];
          int hl = lc >> 5, d = lc & 31;
          int off = pb * 512 + hl * 128 + ((d >> 2) << 4) + (par << 3) +
                    ((d & 3) << 1);
          *(unsigned short*)((char*)pbuf + off) = f2bf(val);
        }
      }
    }
    __syncthreads();
    // coalesced write-out: 64 pair-blocks x 512 B (this block's 4 heads)
    int pix0 = row0, bb2 = 0;
    if (pix0 >= NV_) { bb2 = 1; pix0 -= NV_; }
    int lvl = (pix0 >= 16384) + (pix0 >= 20480) + (pix0 >= 21504);
    int rel0 = pix0 - LSc[lvl];
    char* dst = (char*)C + ((size_t)bb2 * NV_ + LSc[lvl]) * 512 +
                (size_t)(rel0 >> 1) * 1024 + (size_t)(col0 >> 5) * 128;
    int pb = tid >> 2, q = tid & 3;
#pragma unroll
    for (int i = 0; i < 8; ++i) {
      int u = q * 16 + i * 64;
      uint4 vd = *(const uint4*)((const char*)pbuf + pb * 512 + u);
      *(uint4*)(dst + (size_t)pb * 1024 + u) = vd;
    }
  } else {
#pragma unroll
    for (int ni = 0; ni < 4; ++ni) {
      int gcol = col0 + wc * 64 + ni * 16 + (lane & 15);
      float bb = (MODE == 4 && gcol >= 256) ? bias2[gcol - 256] : bias[gcol];
#pragma unroll
      for (int mi = 0; mi < 4; ++mi) {
        int rowbase = row0 + wr * 64 + mi * 16 + ((lane >> 4) << 2);
        f32x4 a = acc[mi][ni];
#pragma unroll
        for (int r = 0; r < 4; ++r) {
          int row = rowbase + r;
          if (row < M) {
            float val = a[r] + bb;
            if constexpr (MODE == 4) {
              if (gcol >= 256)
                C2[(size_t)row * 128 + (gcol - 256)] = f2bf(val);  // attn bf16
              else
                ((float*)C)[(size_t)row * 256 + gcol] = val;
            } else if constexpr (sizeof(OutT) == 2) {
              C[(size_t)row * N + gcol] = (OutT)f2bf(val);
            } else {
              C[(size_t)row * N + gcol] = (OutT)val;
            }
          }
        }
      }
    }
  }
}

// ---------------------------------------------------------------------------
// Sampling v7c: 256-thread block = 2 queries x 2 waves. LEVEL PAIRING
// {0,3}/{1,2} (was {0,1}/{2,3}): each wave gets one L2-thrashing level and
// one cache-resident level, removing the wave-1-idles-at-merge imbalance.
// Phase 1: one (h,l,p) combo per lane (bf16 logits) -> skewed 32-B slot.
// Phase 2: 16 x 8-B gathers per level. Phase 3: LDS wave-pair merge.
// ---------------------------------------------------------------------------
__global__ __launch_bounds__(256) void msda_sample7(
    const char* __restrict__ v,                    // pair-packed bf16
    const float* __restrict__ off,                 // (MQ, 256) fp32
    const unsigned short* __restrict__ attnlg,     // (MQ, 128) bf16
    ushort4* __restrict__ tmp4) {                  // (MQ, 64) bf16 (h,d)
  __shared__ unsigned coeff[2 * 136 * 8];   // 8704 B; first 2 KB reused
  const int tid = threadIdx.x;
  const int lane = tid & 63;
  const int wid = tid >> 6;        // 0..3
  const int wq = wid >> 1;         // query-in-block 0..1
  const int w = wid & 1;           // level-half
  const int bq = blockIdx.x * 2 + wq;
  const int b = (blockIdx.x * 2) / NQ_;   // block-uniform (no straddle)

  unsigned* cbase = coeff + wq * (136 * 8);
  const float* offq = off + (size_t)bq * 256;
  const unsigned short* attq = attnlg + (size_t)bq * 128;

  // ---- phase 1: one combo per lane
  {
    int h = lane >> 3, dl = (lane >> 2) & 1, p = lane & 3;
    int l = dl ? (3 - w) : w;            // wave 0: {0,3}; wave 1: {1,2}
    int Wl = 128 >> l, sh = 7 - l;

    uint2 lg = *(const uint2*)(attq + h * 16 + l * 4);
    float l0 = __builtin_bit_cast(float, lg.x << 16);
    float l1 = __builtin_bit_cast(float, lg.x & 0xFFFF0000u);
    float l2 = __builtin_bit_cast(float, lg.y << 16);
    float l3 = __builtin_bit_cast(float, lg.y & 0xFFFF0000u);
    float m = fmaxf(fmaxf(l0, l1), fmaxf(l2, l3));
    float e0 = expf(l0 - m), e1 = expf(l1 - m);
    float e2 = expf(l2 - m), e3 = expf(l3 - m);
    float ep = (p == 0) ? e0 : (p == 1) ? e1 : (p == 2) ? e2 : e3;
    float wsm = ep / (e0 + e1 + e2 + e3);

    float gx = offq[h * 32 + (l * 4 + p) * 2 + 0];
    float gy = offq[h * 32 + (l * 4 + p) * 2 + 1];
    float s = 0.5f * (float)(Wl - 1);
    float px = fmaf(gx, s, s), py = fmaf(gy, s, s);
    float x0f = floorf(px), y0f = floorf(py);
    float wx = px - x0f, wy = py - y0f;
    int x0 = (int)x0f, y0 = (int)y0f;

    bool bx0 = (unsigned)x0 < (unsigned)Wl, bx1 = (unsigned)(x0 + 1) < (unsigned)Wl;
    bool by0 = (unsigned)y0 < (unsigned)Wl, by1 = (unsigned)(y0 + 1) < (unsigned)Wl;
    int x0c = min(max(x0, 0), Wl - 1), x1c = min(max(x0 + 1, 0), Wl - 1);
    int y0c = min(max(y0, 0), Wl - 1), y1c = min(max(y0 + 1, 0), Wl - 1);

    auto poff = [&](int xx, int yy) -> unsigned {
      return ((unsigned)((yy << (sh - 1)) + (xx >> 1)) << 10) |
             ((unsigned)(xx & 1) << 3);
    };

    float wxm = 1.f - wx, wym = 1.f - wy;
    float w00 = (bx0 & by0) ? wsm * wxm * wym : 0.f;
    float w01 = (bx1 & by0) ? wsm * wx  * wym : 0.f;
    float w10 = (bx0 & by1) ? wsm * wxm * wy  : 0.f;
    float w11 = (bx1 & by1) ? wsm * wx  * wy  : 0.f;

    unsigned* slot = cbase + (h * 17 + l * 4 + p) * 8;
    uint4 s0;
    s0.x = poff(x0c, y0c);
    s0.y = poff(x1c, y0c);
    s0.z = poff(x0c, y1c);
    s0.w = poff(x1c, y1c);
    *(uint4*)slot = s0;
    uint4 s1;
    s1.x = __builtin_bit_cast(unsigned, w00);
    s1.y = __builtin_bit_cast(unsigned, w01);
    s1.z = __builtin_bit_cast(unsigned, w10);
    s1.w = __builtin_bit_cast(unsigned, w11);
    *(uint4*)(slot + 4) = s1;
  }
  __syncthreads();

  // ---- phase 2: this wave's two levels {w, 3-w}
  const int h = lane >> 3, c4 = lane & 7;
  const unsigned laneoff = (unsigned)(h * 128 + c4 * 16);
  float4 acc = make_float4(0.f, 0.f, 0.f, 0.f);

#pragma unroll
  for (int dl = 0; dl < 2; ++dl) {
    const int l = dl ? (3 - w) : w;
    const char* lb = v + ((size_t)b * NV_ + LSc[l]) * 512;
    const unsigned* cb = cbase + (h * 17 + l * 4) * 8;
#pragma unroll
    for (int p = 0; p < 4; ++p) {
      uint4 s0 = *(const uint4*)(cb + p * 8);
      uint4 s1 = *(const uint4*)(cb + p * 8 + 4);
      float w00 = __builtin_bit_cast(float, s1.x);
      float w01 = __builtin_bit_cast(float, s1.y);
      float w10 = __builtin_bit_cast(float, s1.z);
      float w11 = __builtin_bit_cast(float, s1.w);

      uint2 r00 = *(const uint2*)(lb + (laneoff + s0.x));
      uint2 r01 = *(const uint2*)(lb + (laneoff + s0.y));
      uint2 r10 = *(const uint2*)(lb + (laneoff + s0.z));
      uint2 r11 = *(const uint2*)(lb + (laneoff + s0.w));

      acc.x += w00 * __builtin_bit_cast(float, r00.x << 16)
             + w01 * __builtin_bit_cast(float, r01.x << 16)
             + w10 * __builtin_bit_cast(float, r10.x << 16)
             + w11 * __builtin_bit_cast(float, r11.x << 16);
      acc.y += w00 * __builtin_bit_cast(float, r00.x & 0xFFFF0000u)
             + w01 * __builtin_bit_cast(float, r01.x & 0xFFFF0000u)
             + w10 * __builtin_bit_cast(float, r10.x & 0xFFFF0000u)
             + w11 * __builtin_bit_cast(float, r11.x & 0xFFFF0000u);
      acc.z += w00 * __builtin_bit_cast(float, r00.y << 16)
             + w01 * __builtin_bit_cast(float, r01.y << 16)
             + w10 * __builtin_bit_cast(float, r10.y << 16)
             + w11 * __builtin_bit_cast(float, r11.y << 16);
      acc.w += w00 * __builtin_bit_cast(float, r00.y & 0xFFFF0000u)
             + w01 * __builtin_bit_cast(float, r01.y & 0xFFFF0000u)
             + w10 * __builtin_bit_cast(float, r10.y & 0xFFFF0000u)
             + w11 * __builtin_bit_cast(float, r11.y & 0xFFFF0000u);
    }
  }

  // ---- phase 3: merge wave pairs via LDS (coeff dead after barrier)
  __syncthreads();
  float4* red = (float4*)coeff;    // 2 q x 64 lanes x 16 B = 2048 B
  if (w == 1) red[wq * 64 + lane] = acc;
  __syncthreads();
  if (w == 0) {
    float4 o2 = red[wq * 64 + lane];
    acc.x += o2.x; acc.y += o2.y; acc.z += o2.z; acc.w += o2.w;
    ushort4 o;
    o.x = f2bf(acc.x); o.y = f2bf(acc.y); o.z = f2bf(acc.z); o.w = f2bf(acc.w);
    tmp4[(size_t)bq * 64 + lane] = o;
  }
}

// ---------------------------------------------------------------------------
extern "C" void kernel_launch(void* const* d_in, const int* in_sizes, int n_in,
                              void* d_out, int out_size, void* d_ws, size_t ws_size,
                              hipStream_t stream) {
  const float* query  = (const float*)d_in[0];
  // d_in[1] = key (unused)
  const float* value  = (const float*)d_in[2];
  const float* W_off  = (const float*)d_in[3];
  const float* b_off  = (const float*)d_in[4];
  const float* W_attn = (const float*)d_in[5];
  const float* b_attn = (const float*)d_in[6];
  const float* W_v    = (const float*)d_in[7];
  const float* b_v    = (const float*)d_in[8];
  const float* W_out  = (const float*)d_in[9];
  const float* b_out  = (const float*)d_in[10];
  float* out = (float*)d_out;

  char* p = (char*)d_ws;
  unsigned short* v_bf  = (unsigned short*)p; p += (size_t)MV * 256 * 2;   // 22.3 MB
  float*          off_w = (float*)p;          p += (size_t)MQ * 256 * 4;   // 20.5 MB
  unsigned short* att_w = (unsigned short*)p; p += (size_t)MQ * 128 * 2;   //  5.1 MB
  unsigned short* tmp_bf= (unsigned short*)p; p += (size_t)MQ * 256 * 2;   // 10.2 MB
  unsigned short* q_hi  = (unsigned short*)p; p += (size_t)MQ * 256 * 2;   // 10.2 MB
  unsigned short* q_lo  = (unsigned short*)p; p += (size_t)MQ * 256 * 2;   // 10.2 MB
  unsigned short* WvT   = (unsigned short*)p; p += 256 * 256 * 2;
  unsigned short* WoutT = (unsigned short*)p; p += 256 * 256 * 2;
  unsigned short* WqHi  = (unsigned short*)p; p += 384 * 256 * 2;
  unsigned short* WqLo  = (unsigned short*)p; p += 384 * 256 * 2;

  prep_weights<<<dim3(896), dim3(256), 0, stream>>>(
      W_v, W_attn, W_off, W_out, WvT, WoutT, WqHi, WqLo);

  split_query<<<dim3(MQ / 4), dim3(256), 0, stream>>>(
      (const float4*)query, (ushort4*)q_hi, (ushort4*)q_lo);

  // v = value @ W_v + b_v  (bf16, pair-packed, LDS-coalesced epilogue)
  gemm_mfma<1, unsigned short, true><<<dim3(MV / 128, 2), dim3(256), 0, stream>>>(
      value, nullptr, WvT, nullptr, b_v, nullptr, v_bf, nullptr, MV, 256);

  // fused q projections: cols 0-255 -> off fp32 (3-term bf16, all staging
  // via global_load_lds), 256-383 -> attn bf16 (1-term)
  gemm_mfma<4, float><<<dim3((MQ + 127) / 128, 3), dim3(256), 0, stream>>>(
      q_hi, q_lo, WqHi, WqLo, b_off, b_attn, off_w, att_w, MQ, 384);

  // bilinear sampling + softmax-weighted accumulation (2 waves / query)
  msda_sample7<<<dim3(MQ / 2), dim3(256), 0, stream>>>(
      (const char*)v_bf, off_w, att_w, (ushort4*)tmp_bf);

  // out = tmp @ W_out + b_out
  gemm_mfma<0, float><<<dim3((MQ + 127) / 128, 2), dim3(256), 0, stream>>>(
      tmp_bf, nullptr, WoutT, nullptr, b_out, nullptr, out, nullptr, MQ, 256);
}

// Round 16
// 125.164 us; speedup vs baseline: 1.0097x; 1.0097x over previous
//
#include <hip/hip_runtime.h>
#include <math.h>

#define B_   2
#define NQ_  10000
#define NV_  21760
#define EMB  256
#define MQ   (B_*NQ_)   // 20000
#define MV   (B_*NV_)   // 43520

typedef short bf16x8 __attribute__((ext_vector_type(8)));
typedef float f32x4  __attribute__((ext_vector_type(4)));

__device__ constexpr int LSc[4] = {0, 16384, 20480, 21504};

__device__ __forceinline__ unsigned short f2bf(float x) {
  unsigned u = __builtin_bit_cast(unsigned, x);
  u += 0x7FFFu + ((u >> 16) & 1u);
  return (unsigned short)(u >> 16);
}
__device__ __forceinline__ float bf2f(unsigned short s) {
  return __builtin_bit_cast(float, (unsigned)s << 16);
}

// ---------------------------------------------------------------------------
// Weight prep v2 — coalesced transpose via LDS.
// 28 blocks: 8 Wv stripes + 8 Wout + 8 Woff + 4 Wattn (32 output rows each).
// ---------------------------------------------------------------------------
__global__ __launch_bounds__(256) void prep_weights(
    const float* __restrict__ Wv, const float* __restrict__ Wattn,
    const float* __restrict__ Woff, const float* __restrict__ Wout,
    unsigned short* __restrict__ WvT, unsigned short* __restrict__ WoutT,
    unsigned short* __restrict__ WqHi, unsigned short* __restrict__ WqLo) {
  __shared__ float tile[32][257];
  const int bid = blockIdx.x;
  const float* src;
  int n0, which, ncols;
  if (bid < 8)       { which = 0; src = Wv;    n0 = bid * 32;        ncols = 256; }
  else if (bid < 16) { which = 1; src = Wout;  n0 = (bid - 8) * 32;  ncols = 256; }
  else if (bid < 24) { which = 2; src = Woff;  n0 = (bid - 16) * 32; ncols = 256; }
  else               { which = 3; src = Wattn; n0 = (bid - 24) * 32; ncols = 128; }

  const int tc = threadIdx.x & 31;   // col within stripe
  const int tk = threadIdx.x >> 5;   // 0..7
#pragma unroll
  for (int i = 0; i < 32; ++i) {
    int k = tk + 8 * i;
    tile[tc][k] = src[(size_t)k * ncols + n0 + tc];
  }
  __syncthreads();

  const int n = threadIdx.x >> 3;          // 0..31 (output row within stripe)
  const int kc = (threadIdx.x & 7) * 32;   // k-chunk
  unsigned short* dh;
  unsigned short* dl = nullptr;
  if (which == 0)      dh = WvT   + (size_t)(n0 + n) * 256;
  else if (which == 1) dh = WoutT + (size_t)(n0 + n) * 256;
  else if (which == 2) { dh = WqHi + (size_t)(n0 + n) * 256;
                         dl = WqLo + (size_t)(n0 + n) * 256; }
  else                 { dh = WqHi + (size_t)(256 + n0 + n) * 256;
                         dl = WqLo + (size_t)(256 + n0 + n) * 256; }
#pragma unroll
  for (int j = 0; j < 32; ++j) {
    float x = tile[n][kc + j];
    unsigned short hi = f2bf(x);
    dh[kc + j] = hi;
    if (dl) dl[kc + j] = f2bf(x - bf2f(hi));
  }
}

// ---------------------------------------------------------------------------
// MFMA GEMM (R13 form). 128x128 tile, BK=32, 4 waves (2x2), 4x4 frags/wave.
// bf16 staging via global_load_lds(16B): linear LDS dest, pre-swizzled src.
// MODE 0: A bf16, 1-term.   MODE 1: A fp32 (cvt in staging), 1-term.
// MODE 3: A fp32 split hi/lo in staging; 3-term for col0<256 (off cols),
//         1-term for col0>=256 (attn cols, bf16 out via C2).
// VPERM:  v-proj epilogue -> pair-packed bf16 v via LDS + coalesced stores.
// ---------------------------------------------------------------------------
template <int MODE, typename OutT, bool VPERM = false>
__global__ __launch_bounds__(256) void gemm_mfma(
    const void* __restrict__ Aa,
    const unsigned short* __restrict__ Bt, const unsigned short* __restrict__ Bt2,
    const float* __restrict__ bias, const float* __restrict__ bias2,
    OutT* __restrict__ C, unsigned short* __restrict__ C2, int M, int N) {
  constexpr int BM = 128, BK = 32;
  constexpr int SMEM_SHORTS = (MODE == 3 || VPERM) ? 16384 : 8192;
  __shared__ unsigned short smem[SMEM_SHORTS];
  unsigned short* As  = smem;
  unsigned short* Bs  = smem + ((MODE == 3) ? 2 : 1) * BM * BK;
  unsigned short* As2 = smem + BM * BK;       // MODE3 only
  unsigned short* Bs2 = smem + 3 * BM * BK;   // MODE3 only

  const int tid = threadIdx.x;
  const int lane = tid & 63, wv = tid >> 6;
  const int wr = wv >> 1, wc = wv & 1;
  const int row0 = blockIdx.x * BM, col0 = blockIdx.y * BM;

  auto lds_addr = [](int row, int kslot) -> int {
    return row * 64 + ((kslot ^ ((row >> 1) & 3)) << 4);
  };

  auto stage_bf = [&](unsigned short* dst, const unsigned short* src,
                      int rbase, int rmax, int kk) {
#pragma unroll
    for (int i = 0; i < 2; ++i) {
      int idx = tid + 256 * i;
      int row = idx >> 2, ks = idx & 3;
      int rg = min(rbase + row, rmax);
      int xorb = (row >> 1) & 3;
      const unsigned short* gp =
          src + (size_t)rg * 256 + kk + ((ks ^ xorb) << 3);
      unsigned short* lp = dst + (size_t)(wv * 64 + i * 256) * 8;
      __builtin_amdgcn_global_load_lds(
          (const __attribute__((address_space(1))) void*)gp,
          (__attribute__((address_space(3))) void*)lp, 16, 0, 0);
    }
  };
  auto stage_cvt = [&](unsigned short* dst, const float* src,
                       int rbase, int rmax, int kk) {
#pragma unroll
    for (int i = 0; i < 4; ++i) {
      int idx = tid + 256 * i;
      int row = idx >> 3, c4 = idx & 7;
      int rg = min(rbase + row, rmax);
      float4 vdat = *(const float4*)(src + (size_t)rg * 256 + kk + c4 * 4);
      ushort4 o;
      o.x = f2bf(vdat.x); o.y = f2bf(vdat.y);
      o.z = f2bf(vdat.z); o.w = f2bf(vdat.w);
      *(ushort4*)((char*)dst + lds_addr(row, c4 >> 1) + (c4 & 1) * 8) = o;
    }
  };
  auto stage_cvt2 = [&](unsigned short* dstH, unsigned short* dstL,
                        const float* src, int rbase, int rmax, int kk) {
#pragma unroll
    for (int i = 0; i < 4; ++i) {
      int idx = tid + 256 * i;
      int row = idx >> 3, c4 = idx & 7;
      int rg = min(rbase + row, rmax);
      float4 vdat = *(const float4*)(src + (size_t)rg * 256 + kk + c4 * 4);
      ushort4 hh, ll;
      hh.x = f2bf(vdat.x); ll.x = f2bf(vdat.x - bf2f(hh.x));
      hh.y = f2bf(vdat.y); ll.y = f2bf(vdat.y - bf2f(hh.y));
      hh.z = f2bf(vdat.z); ll.z = f2bf(vdat.z - bf2f(hh.z));
      hh.w = f2bf(vdat.w); ll.w = f2bf(vdat.w - bf2f(hh.w));
      int a = lds_addr(row, c4 >> 1) + (c4 & 1) * 8;
      *(ushort4*)((char*)dstH + a) = hh;
      *(ushort4*)((char*)dstL + a) = ll;
    }
  };

  const bool three_term = (MODE == 3) && (col0 < 256);

  f32x4 acc[4][4] = {};

  for (int kk = 0; kk < 256; kk += BK) {
    if (kk) __syncthreads();
    if constexpr (MODE == 1)
      stage_cvt(As, (const float*)Aa, row0, M - 1, kk);
    else if constexpr (MODE == 3) {
      if (three_term)
        stage_cvt2(As, As2, (const float*)Aa, row0, M - 1, kk);
      else
        stage_cvt(As, (const float*)Aa, row0, M - 1, kk);
    } else
      stage_bf(As, (const unsigned short*)Aa, row0, M - 1, kk);
    stage_bf(Bs, Bt, col0, N - 1, kk);
    if constexpr (MODE == 3)
      if (three_term) stage_bf(Bs2, Bt2, col0, N - 1, kk);
    __syncthreads();

    const int kslot = lane >> 4;
    bf16x8 af[4], bfr[4];
#pragma unroll
    for (int i = 0; i < 4; ++i) {
      int ra = wr * 64 + i * 16 + (lane & 15);
      af[i] = *(const bf16x8*)((const char*)As + lds_addr(ra, kslot));
      int rb = wc * 64 + i * 16 + (lane & 15);
      bfr[i] = *(const bf16x8*)((const char*)Bs + lds_addr(rb, kslot));
    }
#pragma unroll
    for (int mi = 0; mi < 4; ++mi)
#pragma unroll
      for (int ni = 0; ni < 4; ++ni)
        acc[mi][ni] = __builtin_amdgcn_mfma_f32_16x16x32_bf16(
            af[mi], bfr[ni], acc[mi][ni], 0, 0, 0);

    if constexpr (MODE == 3) {
      if (three_term) {
        bf16x8 af2[4], bfr2[4];
#pragma unroll
        for (int i = 0; i < 4; ++i) {
          int ra = wr * 64 + i * 16 + (lane & 15);
          af2[i] = *(const bf16x8*)((const char*)As2 + lds_addr(ra, kslot));
          int rb = wc * 64 + i * 16 + (lane & 15);
          bfr2[i] = *(const bf16x8*)((const char*)Bs2 + lds_addr(rb, kslot));
        }
#pragma unroll
        for (int mi = 0; mi < 4; ++mi)
#pragma unroll
          for (int ni = 0; ni < 4; ++ni) {
            acc[mi][ni] = __builtin_amdgcn_mfma_f32_16x16x32_bf16(
                af2[mi], bfr[ni], acc[mi][ni], 0, 0, 0);
            acc[mi][ni] = __builtin_amdgcn_mfma_f32_16x16x32_bf16(
                af[mi], bfr2[ni], acc[mi][ni], 0, 0, 0);
          }
      }
    }
  }

  // epilogue: D frag layout col=lane&15, row=(lane>>4)*4+reg  [m89-verified]
  if constexpr (VPERM) {
    float bb4[4];
#pragma unroll
    for (int ni = 0; ni < 4; ++ni)
      bb4[ni] = bias[col0 + wc * 64 + ni * 16 + (lane & 15)];
    __syncthreads();                 // As/Bs dead; reuse the 32 KB
    unsigned short* pbuf = smem;
#pragma unroll
    for (int mi = 0; mi < 4; ++mi) {
#pragma unroll
      for (int r = 0; r < 4; ++r) {
        int lr = wr * 64 + mi * 16 + ((lane >> 4) << 2) + r;  // local row
        int pb = lr >> 1, par = lr & 1;
#pragma unroll
        for (int ni = 0; ni < 4; ++ni) {
          int lc = wc * 64 + ni * 16 + (lane & 15);
          float val = acc[mi][ni][r] + bb4[ni];
          int hl = lc >> 5, d = lc & 31;
          int off = pb * 512 + hl * 128 + ((d >> 2) << 4) + (par << 3) +
                    ((d & 3) << 1);
          *(unsigned short*)((char*)pbuf + off) = f2bf(val);
        }
      }
    }
    __syncthreads();
    // coalesced write-out: 64 pair-blocks x 512 B (this block's 4 heads)
    int pix0 = row0, bb2 = 0;
    if (pix0 >= NV_) { bb2 = 1; pix0 -= NV_; }
    int lvl = (pix0 >= 16384) + (pix0 >= 20480) + (pix0 >= 21504);
    int rel0 = pix0 - LSc[lvl];
    char* dst = (char*)C + ((size_t)bb2 * NV_ + LSc[lvl]) * 512 +
                (size_t)(rel0 >> 1) * 1024 + (size_t)(col0 >> 5) * 128;
    int pb = tid >> 2, q = tid & 3;
#pragma unroll
    for (int i = 0; i < 8; ++i) {
      int u = q * 16 + i * 64;
      uint4 vd = *(const uint4*)((const char*)pbuf + pb * 512 + u);
      *(uint4*)(dst + (size_t)pb * 1024 + u) = vd;
    }
  } else {
#pragma unroll
    for (int ni = 0; ni < 4; ++ni) {
      int gcol = col0 + wc * 64 + ni * 16 + (lane & 15);
      float bb = (MODE == 3 && gcol >= 256) ? bias2[gcol - 256] : bias[gcol];
#pragma unroll
      for (int mi = 0; mi < 4; ++mi) {
        int rowbase = row0 + wr * 64 + mi * 16 + ((lane >> 4) << 2);
        f32x4 a = acc[mi][ni];
#pragma unroll
        for (int r = 0; r < 4; ++r) {
          int row = rowbase + r;
          if (row < M) {
            float val = a[r] + bb;
            if constexpr (MODE == 3) {
              if (gcol >= 256)
                C2[(size_t)row * 128 + (gcol - 256)] = f2bf(val);  // attn bf16
              else
                ((float*)C)[(size_t)row * 256 + gcol] = val;
            } else if constexpr (sizeof(OutT) == 2) {
              C[(size_t)row * N + gcol] = (OutT)f2bf(val);
            } else {
              C[(size_t)row * N + gcol] = (OutT)val;
            }
          }
        }
      }
    }
  }
}

// ---------------------------------------------------------------------------
// Sampling v7c (measured 53.0 µs): 256-thread block = 2 queries x 2 waves;
// wave w owns levels {w, 3-w}. Phase 1: one (h,l,p) combo per lane (bf16
// logits) -> skewed 32-B slot. Phase 2: 16 x 8-B gathers per level
// (pair-packed bf16 v). Phase 3: LDS wave-pair merge.
// ---------------------------------------------------------------------------
__global__ __launch_bounds__(256) void msda_sample7(
    const char* __restrict__ v,                    // pair-packed bf16
    const float* __restrict__ off,                 // (MQ, 256) fp32
    const unsigned short* __restrict__ attnlg,     // (MQ, 128) bf16
    ushort4* __restrict__ tmp4) {                  // (MQ, 64) bf16 (h,d)
  __shared__ unsigned coeff[2 * 136 * 8];   // 8704 B; first 2 KB reused
  const int tid = threadIdx.x;
  const int lane = tid & 63;
  const int wid = tid >> 6;        // 0..3
  const int wq = wid >> 1;         // query-in-block 0..1
  const int w = wid & 1;           // level-half
  const int bq = blockIdx.x * 2 + wq;
  const int b = (blockIdx.x * 2) / NQ_;   // block-uniform (no straddle)

  unsigned* cbase = coeff + wq * (136 * 8);
  const float* offq = off + (size_t)bq * 256;
  const unsigned short* attq = attnlg + (size_t)bq * 128;

  // ---- phase 1: one combo per lane
  {
    int h = lane >> 3, dl = (lane >> 2) & 1, p = lane & 3;
    int l = dl ? (3 - w) : w;            // wave 0: {0,3}; wave 1: {1,2}
    int Wl = 128 >> l, sh = 7 - l;

    uint2 lg = *(const uint2*)(attq + h * 16 + l * 4);
    float l0 = __builtin_bit_cast(float, lg.x << 16);
    float l1 = __builtin_bit_cast(float, lg.x & 0xFFFF0000u);
    float l2 = __builtin_bit_cast(float, lg.y << 16);
    float l3 = __builtin_bit_cast(float, lg.y & 0xFFFF0000u);
    float m = fmaxf(fmaxf(l0, l1), fmaxf(l2, l3));
    float e0 = expf(l0 - m), e1 = expf(l1 - m);
    float e2 = expf(l2 - m), e3 = expf(l3 - m);
    float ep = (p == 0) ? e0 : (p == 1) ? e1 : (p == 2) ? e2 : e3;
    float wsm = ep / (e0 + e1 + e2 + e3);

    float gx = offq[h * 32 + (l * 4 + p) * 2 + 0];
    float gy = offq[h * 32 + (l * 4 + p) * 2 + 1];
    float s = 0.5f * (float)(Wl - 1);
    float px = fmaf(gx, s, s), py = fmaf(gy, s, s);
    float x0f = floorf(px), y0f = floorf(py);
    float wx = px - x0f, wy = py - y0f;
    int x0 = (int)x0f, y0 = (int)y0f;

    bool bx0 = (unsigned)x0 < (unsigned)Wl, bx1 = (unsigned)(x0 + 1) < (unsigned)Wl;
    bool by0 = (unsigned)y0 < (unsigned)Wl, by1 = (unsigned)(y0 + 1) < (unsigned)Wl;
    int x0c = min(max(x0, 0), Wl - 1), x1c = min(max(x0 + 1, 0), Wl - 1);
    int y0c = min(max(y0, 0), Wl - 1), y1c = min(max(y0 + 1, 0), Wl - 1);

    auto poff = [&](int xx, int yy) -> unsigned {
      return ((unsigned)((yy << (sh - 1)) + (xx >> 1)) << 10) |
             ((unsigned)(xx & 1) << 3);
    };

    float wxm = 1.f - wx, wym = 1.f - wy;
    float w00 = (bx0 & by0) ? wsm * wxm * wym : 0.f;
    float w01 = (bx1 & by0) ? wsm * wx  * wym : 0.f;
    float w10 = (bx0 & by1) ? wsm * wxm * wy  : 0.f;
    float w11 = (bx1 & by1) ? wsm * wx  * wy  : 0.f;

    unsigned* slot = cbase + (h * 17 + l * 4 + p) * 8;
    uint4 s0;
    s0.x = poff(x0c, y0c);
    s0.y = poff(x1c, y0c);
    s0.z = poff(x0c, y1c);
    s0.w = poff(x1c, y1c);
    *(uint4*)slot = s0;
    uint4 s1;
    s1.x = __builtin_bit_cast(unsigned, w00);
    s1.y = __builtin_bit_cast(unsigned, w01);
    s1.z = __builtin_bit_cast(unsigned, w10);
    s1.w = __builtin_bit_cast(unsigned, w11);
    *(uint4*)(slot + 4) = s1;
  }
  __syncthreads();

  // ---- phase 2: this wave's two levels {w, 3-w}
  const int h = lane >> 3, c4 = lane & 7;
  const unsigned laneoff = (unsigned)(h * 128 + c4 * 16);
  float4 acc = make_float4(0.f, 0.f, 0.f, 0.f);

#pragma unroll
  for (int dl = 0; dl < 2; ++dl) {
    const int l = dl ? (3 - w) : w;
    const char* lb = v + ((size_t)b * NV_ + LSc[l]) * 512;
    const unsigned* cb = cbase + (h * 17 + l * 4) * 8;
#pragma unroll
    for (int p = 0; p < 4; ++p) {
      uint4 s0 = *(const uint4*)(cb + p * 8);
      uint4 s1 = *(const uint4*)(cb + p * 8 + 4);
      float w00 = __builtin_bit_cast(float, s1.x);
      float w01 = __builtin_bit_cast(float, s1.y);
      float w10 = __builtin_bit_cast(float, s1.z);
      float w11 = __builtin_bit_cast(float, s1.w);

      uint2 r00 = *(const uint2*)(lb + (laneoff + s0.x));
      uint2 r01 = *(const uint2*)(lb + (laneoff + s0.y));
      uint2 r10 = *(const uint2*)(lb + (laneoff + s0.z));
      uint2 r11 = *(const uint2*)(lb + (laneoff + s0.w));

      acc.x += w00 * __builtin_bit_cast(float, r00.x << 16)
             + w01 * __builtin_bit_cast(float, r01.x << 16)
             + w10 * __builtin_bit_cast(float, r10.x << 16)
             + w11 * __builtin_bit_cast(float, r11.x << 16);
      acc.y += w00 * __builtin_bit_cast(float, r00.x & 0xFFFF0000u)
             + w01 * __builtin_bit_cast(float, r01.x & 0xFFFF0000u)
             + w10 * __builtin_bit_cast(float, r10.x & 0xFFFF0000u)
             + w11 * __builtin_bit_cast(float, r11.x & 0xFFFF0000u);
      acc.z += w00 * __builtin_bit_cast(float, r00.y << 16)
             + w01 * __builtin_bit_cast(float, r01.y << 16)
             + w10 * __builtin_bit_cast(float, r10.y << 16)
             + w11 * __builtin_bit_cast(float, r11.y << 16);
      acc.w += w00 * __builtin_bit_cast(float, r00.y & 0xFFFF0000u)
             + w01 * __builtin_bit_cast(float, r01.y & 0xFFFF0000u)
             + w10 * __builtin_bit_cast(float, r10.y & 0xFFFF0000u)
             + w11 * __builtin_bit_cast(float, r11.y & 0xFFFF0000u);
    }
  }

  // ---- phase 3: merge wave pairs via LDS (coeff dead after barrier)
  __syncthreads();
  float4* red = (float4*)coeff;    // 2 q x 64 lanes x 16 B = 2048 B
  if (w == 1) red[wq * 64 + lane] = acc;
  __syncthreads();
  if (w == 0) {
    float4 o2 = red[wq * 64 + lane];
    acc.x += o2.x; acc.y += o2.y; acc.z += o2.z; acc.w += o2.w;
    ushort4 o;
    o.x = f2bf(acc.x); o.y = f2bf(acc.y); o.z = f2bf(acc.z); o.w = f2bf(acc.w);
    tmp4[(size_t)bq * 64 + lane] = o;
  }
}

// ---------------------------------------------------------------------------
extern "C" void kernel_launch(void* const* d_in, const int* in_sizes, int n_in,
                              void* d_out, int out_size, void* d_ws, size_t ws_size,
                              hipStream_t stream) {
  const float* query  = (const float*)d_in[0];
  // d_in[1] = key (unused)
  const float* value  = (const float*)d_in[2];
  const float* W_off  = (const float*)d_in[3];
  const float* b_off  = (const float*)d_in[4];
  const float* W_attn = (const float*)d_in[5];
  const float* b_attn = (const float*)d_in[6];
  const float* W_v    = (const float*)d_in[7];
  const float* b_v    = (const float*)d_in[8];
  const float* W_out  = (const float*)d_in[9];
  const float* b_out  = (const float*)d_in[10];
  float* out = (float*)d_out;

  char* p = (char*)d_ws;
  unsigned short* v_bf  = (unsigned short*)p; p += (size_t)MV * 256 * 2;   // 22.3 MB
  float*          off_w = (float*)p;          p += (size_t)MQ * 256 * 4;   // 20.5 MB
  unsigned short* att_w = (unsigned short*)p; p += (size_t)MQ * 128 * 2;   //  5.1 MB
  unsigned short* tmp_bf= (unsigned short*)p; p += (size_t)MQ * 256 * 2;   // 10.2 MB
  unsigned short* WvT   = (unsigned short*)p; p += 256 * 256 * 2;
  unsigned short* WoutT = (unsigned short*)p; p += 256 * 256 * 2;
  unsigned short* WqHi  = (unsigned short*)p; p += 384 * 256 * 2;
  unsigned short* WqLo  = (unsigned short*)p; p += 384 * 256 * 2;

  prep_weights<<<dim3(28), dim3(256), 0, stream>>>(
      W_v, W_attn, W_off, W_out, WvT, WoutT, WqHi, WqLo);

  // v = value @ W_v + b_v  (bf16, pair-packed, LDS-coalesced epilogue)
  gemm_mfma<1, unsigned short, true><<<dim3(MV / 128, 2), dim3(256), 0, stream>>>(
      value, WvT, nullptr, b_v, nullptr, v_bf, nullptr, MV, 256);

  // fused q projections: cols 0-255 -> off fp32 (3-term), 256-383 -> attn bf16
  gemm_mfma<3, float><<<dim3((MQ + 127) / 128, 3), dim3(256), 0, stream>>>(
      query, WqHi, WqLo, b_off, b_attn, off_w, att_w, MQ, 384);

  // bilinear sampling + softmax-weighted accumulation (2 waves / query)
  msda_sample7<<<dim3(MQ / 2), dim3(256), 0, stream>>>(
      (const char*)v_bf, off_w, att_w, (ushort4*)tmp_bf);

  // out = tmp @ W_out + b_out
  gemm_mfma<0, float><<<dim3((MQ + 127) / 128, 2), dim3(256), 0, stream>>>(
      tmp_bf, WoutT, nullptr, b_out, nullptr, out, nullptr, MQ, 256);
}

// Round 17
// 120.851 us; speedup vs baseline: 1.0458x; 1.0357x over previous
//
#include <hip/hip_runtime.h>
#include <math.h>

#define B_   2
#define NQ_  10000
#define NV_  21760
#define EMB  256
#define MQ   (B_*NQ_)   // 20000
#define MV   (B_*NV_)   // 43520

typedef short bf16x8 __attribute__((ext_vector_type(8)));
typedef float f32x4  __attribute__((ext_vector_type(4)));
typedef float f32x2  __attribute__((ext_vector_type(2)));

__device__ constexpr int LSc[4] = {0, 16384, 20480, 21504};

__device__ __forceinline__ unsigned short f2bf(float x) {
  unsigned u = __builtin_bit_cast(unsigned, x);
  u += 0x7FFFu + ((u >> 16) & 1u);
  return (unsigned short)(u >> 16);
}
__device__ __forceinline__ float bf2f(unsigned short s) {
  return __builtin_bit_cast(float, (unsigned)s << 16);
}

// ---------------------------------------------------------------------------
// Weight prep v1 (R13's measured-good version: 896 tiny blocks; reads are
// uncoalesced but total 1.25 MB -> L2-absorbed; beats the 28-block
// "coalesced" v2 by ~5 us [R16 measurement]).
// ---------------------------------------------------------------------------
__global__ __launch_bounds__(256) void prep_weights(
    const float* __restrict__ Wv, const float* __restrict__ Wattn,
    const float* __restrict__ Woff, const float* __restrict__ Wout,
    unsigned short* __restrict__ WvT, unsigned short* __restrict__ WoutT,
    unsigned short* __restrict__ WqHi, unsigned short* __restrict__ WqLo) {
  int n = blockIdx.x;       // 0..895
  int k = threadIdx.x;      // 0..255
  if (n < 256) {
    WvT[n * 256 + k] = f2bf(Wv[k * 256 + n]);
  } else if (n < 512) {
    int c = n - 256;
    WoutT[c * 256 + k] = f2bf(Wout[k * 256 + c]);
  } else {
    int qr = n - 512;       // 0..383
    float x = (qr < 256) ? Woff[k * 256 + qr] : Wattn[k * 128 + (qr - 256)];
    unsigned short hi = f2bf(x);
    WqHi[qr * 256 + k] = hi;
    WqLo[qr * 256 + k] = f2bf(x - bf2f(hi));
  }
}

// ---------------------------------------------------------------------------
// MFMA GEMM (R13 form). 128x128 tile, BK=32, 4 waves (2x2), 4x4 frags/wave.
// bf16 staging via global_load_lds(16B): linear LDS dest, pre-swizzled src.
// MODE 0: A bf16, 1-term.   MODE 1: A fp32 (cvt in staging), 1-term.
// MODE 3: A fp32 split hi/lo in staging; 3-term for col0<256 (off cols),
//         1-term for col0>=256 (attn cols, bf16 out via C2).
// VPERM:  v-proj epilogue -> pair-packed bf16 v via LDS + coalesced stores.
// ---------------------------------------------------------------------------
template <int MODE, typename OutT, bool VPERM = false>
__global__ __launch_bounds__(256) void gemm_mfma(
    const void* __restrict__ Aa,
    const unsigned short* __restrict__ Bt, const unsigned short* __restrict__ Bt2,
    const float* __restrict__ bias, const float* __restrict__ bias2,
    OutT* __restrict__ C, unsigned short* __restrict__ C2, int M, int N) {
  constexpr int BM = 128, BK = 32;
  constexpr int SMEM_SHORTS = (MODE == 3 || VPERM) ? 16384 : 8192;
  __shared__ unsigned short smem[SMEM_SHORTS];
  unsigned short* As  = smem;
  unsigned short* Bs  = smem + ((MODE == 3) ? 2 : 1) * BM * BK;
  unsigned short* As2 = smem + BM * BK;       // MODE3 only
  unsigned short* Bs2 = smem + 3 * BM * BK;   // MODE3 only

  const int tid = threadIdx.x;
  const int lane = tid & 63, wv = tid >> 6;
  const int wr = wv >> 1, wc = wv & 1;
  const int row0 = blockIdx.x * BM, col0 = blockIdx.y * BM;

  auto lds_addr = [](int row, int kslot) -> int {
    return row * 64 + ((kslot ^ ((row >> 1) & 3)) << 4);
  };

  auto stage_bf = [&](unsigned short* dst, const unsigned short* src,
                      int rbase, int rmax, int kk) {
#pragma unroll
    for (int i = 0; i < 2; ++i) {
      int idx = tid + 256 * i;
      int row = idx >> 2, ks = idx & 3;
      int rg = min(rbase + row, rmax);
      int xorb = (row >> 1) & 3;
      const unsigned short* gp =
          src + (size_t)rg * 256 + kk + ((ks ^ xorb) << 3);
      unsigned short* lp = dst + (size_t)(wv * 64 + i * 256) * 8;
      __builtin_amdgcn_global_load_lds(
          (const __attribute__((address_space(1))) void*)gp,
          (__attribute__((address_space(3))) void*)lp, 16, 0, 0);
    }
  };
  auto stage_cvt = [&](unsigned short* dst, const float* src,
                       int rbase, int rmax, int kk) {
#pragma unroll
    for (int i = 0; i < 4; ++i) {
      int idx = tid + 256 * i;
      int row = idx >> 3, c4 = idx & 7;
      int rg = min(rbase + row, rmax);
      float4 vdat = *(const float4*)(src + (size_t)rg * 256 + kk + c4 * 4);
      ushort4 o;
      o.x = f2bf(vdat.x); o.y = f2bf(vdat.y);
      o.z = f2bf(vdat.z); o.w = f2bf(vdat.w);
      *(ushort4*)((char*)dst + lds_addr(row, c4 >> 1) + (c4 & 1) * 8) = o;
    }
  };
  auto stage_cvt2 = [&](unsigned short* dstH, unsigned short* dstL,
                        const float* src, int rbase, int rmax, int kk) {
#pragma unroll
    for (int i = 0; i < 4; ++i) {
      int idx = tid + 256 * i;
      int row = idx >> 3, c4 = idx & 7;
      int rg = min(rbase + row, rmax);
      float4 vdat = *(const float4*)(src + (size_t)rg * 256 + kk + c4 * 4);
      ushort4 hh, ll;
      hh.x = f2bf(vdat.x); ll.x = f2bf(vdat.x - bf2f(hh.x));
      hh.y = f2bf(vdat.y); ll.y = f2bf(vdat.y - bf2f(hh.y));
      hh.z = f2bf(vdat.z); ll.z = f2bf(vdat.z - bf2f(hh.z));
      hh.w = f2bf(vdat.w); ll.w = f2bf(vdat.w - bf2f(hh.w));
      int a = lds_addr(row, c4 >> 1) + (c4 & 1) * 8;
      *(ushort4*)((char*)dstH + a) = hh;
      *(ushort4*)((char*)dstL + a) = ll;
    }
  };

  const bool three_term = (MODE == 3) && (col0 < 256);

  f32x4 acc[4][4] = {};

  for (int kk = 0; kk < 256; kk += BK) {
    if (kk) __syncthreads();
    if constexpr (MODE == 1)
      stage_cvt(As, (const float*)Aa, row0, M - 1, kk);
    else if constexpr (MODE == 3) {
      if (three_term)
        stage_cvt2(As, As2, (const float*)Aa, row0, M - 1, kk);
      else
        stage_cvt(As, (const float*)Aa, row0, M - 1, kk);
    } else
      stage_bf(As, (const unsigned short*)Aa, row0, M - 1, kk);
    stage_bf(Bs, Bt, col0, N - 1, kk);
    if constexpr (MODE == 3)
      if (three_term) stage_bf(Bs2, Bt2, col0, N - 1, kk);
    __syncthreads();

    const int kslot = lane >> 4;
    bf16x8 af[4], bfr[4];
#pragma unroll
    for (int i = 0; i < 4; ++i) {
      int ra = wr * 64 + i * 16 + (lane & 15);
      af[i] = *(const bf16x8*)((const char*)As + lds_addr(ra, kslot));
      int rb = wc * 64 + i * 16 + (lane & 15);
      bfr[i] = *(const bf16x8*)((const char*)Bs + lds_addr(rb, kslot));
    }
#pragma unroll
    for (int mi = 0; mi < 4; ++mi)
#pragma unroll
      for (int ni = 0; ni < 4; ++ni)
        acc[mi][ni] = __builtin_amdgcn_mfma_f32_16x16x32_bf16(
            af[mi], bfr[ni], acc[mi][ni], 0, 0, 0);

    if constexpr (MODE == 3) {
      if (three_term) {
        bf16x8 af2[4], bfr2[4];
#pragma unroll
        for (int i = 0; i < 4; ++i) {
          int ra = wr * 64 + i * 16 + (lane & 15);
          af2[i] = *(const bf16x8*)((const char*)As2 + lds_addr(ra, kslot));
          int rb = wc * 64 + i * 16 + (lane & 15);
          bfr2[i] = *(const bf16x8*)((const char*)Bs2 + lds_addr(rb, kslot));
        }
#pragma unroll
        for (int mi = 0; mi < 4; ++mi)
#pragma unroll
          for (int ni = 0; ni < 4; ++ni) {
            acc[mi][ni] = __builtin_amdgcn_mfma_f32_16x16x32_bf16(
                af2[mi], bfr[ni], acc[mi][ni], 0, 0, 0);
            acc[mi][ni] = __builtin_amdgcn_mfma_f32_16x16x32_bf16(
                af[mi], bfr2[ni], acc[mi][ni], 0, 0, 0);
          }
      }
    }
  }

  // epilogue: D frag layout col=lane&15, row=(lane>>4)*4+reg  [m89-verified]
  if constexpr (VPERM) {
    float bb4[4];
#pragma unroll
    for (int ni = 0; ni < 4; ++ni)
      bb4[ni] = bias[col0 + wc * 64 + ni * 16 + (lane & 15)];
    __syncthreads();                 // As/Bs dead; reuse the 32 KB
    unsigned short* pbuf = smem;
#pragma unroll
    for (int mi = 0; mi < 4; ++mi) {
#pragma unroll
      for (int r = 0; r < 4; ++r) {
        int lr = wr * 64 + mi * 16 + ((lane >> 4) << 2) + r;  // local row
        int pb = lr >> 1, par = lr & 1;
#pragma unroll
        for (int ni = 0; ni < 4; ++ni) {
          int lc = wc * 64 + ni * 16 + (lane & 15);
          float val = acc[mi][ni][r] + bb4[ni];
          int hl = lc >> 5, d = lc & 31;
          int off = pb * 512 + hl * 128 + ((d >> 2) << 4) + (par << 3) +
                    ((d & 3) << 1);
          *(unsigned short*)((char*)pbuf + off) = f2bf(val);
        }
      }
    }
    __syncthreads();
    // coalesced write-out: 64 pair-blocks x 512 B (this block's 4 heads)
    int pix0 = row0, bb2 = 0;
    if (pix0 >= NV_) { bb2 = 1; pix0 -= NV_; }
    int lvl = (pix0 >= 16384) + (pix0 >= 20480) + (pix0 >= 21504);
    int rel0 = pix0 - LSc[lvl];
    char* dst = (char*)C + ((size_t)bb2 * NV_ + LSc[lvl]) * 512 +
                (size_t)(rel0 >> 1) * 1024 + (size_t)(col0 >> 5) * 128;
    int pb = tid >> 2, q = tid & 3;
#pragma unroll
    for (int i = 0; i < 8; ++i) {
      int u = q * 16 + i * 64;
      uint4 vd = *(const uint4*)((const char*)pbuf + pb * 512 + u);
      *(uint4*)(dst + (size_t)pb * 1024 + u) = vd;
    }
  } else {
#pragma unroll
    for (int ni = 0; ni < 4; ++ni) {
      int gcol = col0 + wc * 64 + ni * 16 + (lane & 15);
      float bb = (MODE == 3 && gcol >= 256) ? bias2[gcol - 256] : bias[gcol];
#pragma unroll
      for (int mi = 0; mi < 4; ++mi) {
        int rowbase = row0 + wr * 64 + mi * 16 + ((lane >> 4) << 2);
        f32x4 a = acc[mi][ni];
#pragma unroll
        for (int r = 0; r < 4; ++r) {
          int row = rowbase + r;
          if (row < M) {
            float val = a[r] + bb;
            if constexpr (MODE == 3) {
              if (gcol >= 256)
                C2[(size_t)row * 128 + (gcol - 256)] = f2bf(val);  // attn bf16
              else
                ((float*)C)[(size_t)row * 256 + gcol] = val;
            } else if constexpr (sizeof(OutT) == 2) {
              C[(size_t)row * N + gcol] = (OutT)f2bf(val);
            } else {
              C[(size_t)row * N + gcol] = (OutT)val;
            }
          }
        }
      }
    }
  }
}

// ---------------------------------------------------------------------------
// Sampling v7d: R13's v7b structure (256-thread block = 2 queries x 2 waves,
// wave w owns levels {2w, 2w+1}, bf16 logits, pair-packed v) with the
// accumulate rewritten as float2 __builtin_elementwise_fma so clang can emit
// v_pk_fma_f32 (packed 2xfp32 FMA = the 157TF-peak instruction; scalar fma
// runs at half rate). Worst case: lowers to 2x v_fma (pure R13 revert).
// ---------------------------------------------------------------------------
__global__ __launch_bounds__(256) void msda_sample7(
    const char* __restrict__ v,                    // pair-packed bf16
    const float* __restrict__ off,                 // (MQ, 256) fp32
    const unsigned short* __restrict__ attnlg,     // (MQ, 128) bf16
    ushort4* __restrict__ tmp4) {                  // (MQ, 64) bf16 (h,d)
  __shared__ unsigned coeff[2 * 136 * 8];   // 8704 B; first 2 KB reused
  const int tid = threadIdx.x;
  const int lane = tid & 63;
  const int wid = tid >> 6;        // 0..3
  const int wq = wid >> 1;         // query-in-block 0..1
  const int w = wid & 1;           // level-half
  const int bq = blockIdx.x * 2 + wq;
  const int b = (blockIdx.x * 2) / NQ_;   // block-uniform (no straddle)

  unsigned* cbase = coeff + wq * (136 * 8);
  const float* offq = off + (size_t)bq * 256;
  const unsigned short* attq = attnlg + (size_t)bq * 128;

  // ---- phase 1: one combo per lane
  {
    int h = lane >> 3, dl = (lane >> 2) & 1, p = lane & 3;
    int l = 2 * w + dl;
    int Wl = 128 >> l, sh = 7 - l;

    uint2 lg = *(const uint2*)(attq + h * 16 + l * 4);
    float l0 = __builtin_bit_cast(float, lg.x << 16);
    float l1 = __builtin_bit_cast(float, lg.x & 0xFFFF0000u);
    float l2 = __builtin_bit_cast(float, lg.y << 16);
    float l3 = __builtin_bit_cast(float, lg.y & 0xFFFF0000u);
    float m = fmaxf(fmaxf(l0, l1), fmaxf(l2, l3));
    float e0 = expf(l0 - m), e1 = expf(l1 - m);
    float e2 = expf(l2 - m), e3 = expf(l3 - m);
    float ep = (p == 0) ? e0 : (p == 1) ? e1 : (p == 2) ? e2 : e3;
    float wsm = ep / (e0 + e1 + e2 + e3);

    float gx = offq[h * 32 + (l * 4 + p) * 2 + 0];
    float gy = offq[h * 32 + (l * 4 + p) * 2 + 1];
    float s = 0.5f * (float)(Wl - 1);
    float px = fmaf(gx, s, s), py = fmaf(gy, s, s);
    float x0f = floorf(px), y0f = floorf(py);
    float wx = px - x0f, wy = py - y0f;
    int x0 = (int)x0f, y0 = (int)y0f;

    bool bx0 = (unsigned)x0 < (unsigned)Wl, bx1 = (unsigned)(x0 + 1) < (unsigned)Wl;
    bool by0 = (unsigned)y0 < (unsigned)Wl, by1 = (unsigned)(y0 + 1) < (unsigned)Wl;
    int x0c = min(max(x0, 0), Wl - 1), x1c = min(max(x0 + 1, 0), Wl - 1);
    int y0c = min(max(y0, 0), Wl - 1), y1c = min(max(y0 + 1, 0), Wl - 1);

    auto poff = [&](int xx, int yy) -> unsigned {
      return ((unsigned)((yy << (sh - 1)) + (xx >> 1)) << 10) |
             ((unsigned)(xx & 1) << 3);
    };

    float wxm = 1.f - wx, wym = 1.f - wy;
    float w00 = (bx0 & by0) ? wsm * wxm * wym : 0.f;
    float w01 = (bx1 & by0) ? wsm * wx  * wym : 0.f;
    float w10 = (bx0 & by1) ? wsm * wxm * wy  : 0.f;
    float w11 = (bx1 & by1) ? wsm * wx  * wy  : 0.f;

    unsigned* slot = cbase + (h * 17 + l * 4 + p) * 8;
    uint4 s0;
    s0.x = poff(x0c, y0c);
    s0.y = poff(x1c, y0c);
    s0.z = poff(x0c, y1c);
    s0.w = poff(x1c, y1c);
    *(uint4*)slot = s0;
    uint4 s1;
    s1.x = __builtin_bit_cast(unsigned, w00);
    s1.y = __builtin_bit_cast(unsigned, w01);
    s1.z = __builtin_bit_cast(unsigned, w10);
    s1.w = __builtin_bit_cast(unsigned, w11);
    *(uint4*)(slot + 4) = s1;
  }
  __syncthreads();

  // ---- phase 2: this wave's two levels
  const int h = lane >> 3, c4 = lane & 7;
  const unsigned laneoff = (unsigned)(h * 128 + c4 * 16);
  f32x2 ax = {0.f, 0.f};   // channels {0,1}
  f32x2 az = {0.f, 0.f};   // channels {2,3}

#pragma unroll
  for (int dl = 0; dl < 2; ++dl) {
    const int l = 2 * w + dl;
    const char* lb = v + ((size_t)b * NV_ + LSc[l]) * 512;
    const unsigned* cb = cbase + (h * 17 + l * 4) * 8;
#pragma unroll
    for (int p = 0; p < 4; ++p) {
      uint4 s0 = *(const uint4*)(cb + p * 8);
      uint4 s1 = *(const uint4*)(cb + p * 8 + 4);

      uint2 r00 = *(const uint2*)(lb + (laneoff + s0.x));
      uint2 r01 = *(const uint2*)(lb + (laneoff + s0.y));
      uint2 r10 = *(const uint2*)(lb + (laneoff + s0.z));
      uint2 r11 = *(const uint2*)(lb + (laneoff + s0.w));

      auto fmacc = [&](uint2 r, unsigned wbits) {
        float wv_ = __builtin_bit_cast(float, wbits);
        f32x2 w2 = {wv_, wv_};
        f32x2 vx = {__builtin_bit_cast(float, r.x << 16),
                    __builtin_bit_cast(float, r.x & 0xFFFF0000u)};
        f32x2 vz = {__builtin_bit_cast(float, r.y << 16),
                    __builtin_bit_cast(float, r.y & 0xFFFF0000u)};
        ax = __builtin_elementwise_fma(vx, w2, ax);
        az = __builtin_elementwise_fma(vz, w2, az);
      };
      fmacc(r00, s1.x);
      fmacc(r01, s1.y);
      fmacc(r10, s1.z);
      fmacc(r11, s1.w);
    }
  }

  // ---- phase 3: merge wave pairs via LDS (coeff dead after barrier)
  __syncthreads();
  float4* red = (float4*)coeff;    // 2 q x 64 lanes x 16 B = 2048 B
  if (w == 1) {
    float4 acc;
    acc.x = ax.x; acc.y = ax.y; acc.z = az.x; acc.w = az.y;
    red[wq * 64 + lane] = acc;
  }
  __syncthreads();
  if (w == 0) {
    float4 o2 = red[wq * 64 + lane];
    ushort4 o;
    o.x = f2bf(ax.x + o2.x);
    o.y = f2bf(ax.y + o2.y);
    o.z = f2bf(az.x + o2.z);
    o.w = f2bf(az.y + o2.w);
    tmp4[(size_t)bq * 64 + lane] = o;
  }
}

// ---------------------------------------------------------------------------
extern "C" void kernel_launch(void* const* d_in, const int* in_sizes, int n_in,
                              void* d_out, int out_size, void* d_ws, size_t ws_size,
                              hipStream_t stream) {
  const float* query  = (const float*)d_in[0];
  // d_in[1] = key (unused)
  const float* value  = (const float*)d_in[2];
  const float* W_off  = (const float*)d_in[3];
  const float* b_off  = (const float*)d_in[4];
  const float* W_attn = (const float*)d_in[5];
  const float* b_attn = (const float*)d_in[6];
  const float* W_v    = (const float*)d_in[7];
  const float* b_v    = (const float*)d_in[8];
  const float* W_out  = (const float*)d_in[9];
  const float* b_out  = (const float*)d_in[10];
  float* out = (float*)d_out;

  char* p = (char*)d_ws;
  unsigned short* v_bf  = (unsigned short*)p; p += (size_t)MV * 256 * 2;   // 22.3 MB
  float*          off_w = (float*)p;          p += (size_t)MQ * 256 * 4;   // 20.5 MB
  unsigned short* att_w = (unsigned short*)p; p += (size_t)MQ * 128 * 2;   //  5.1 MB
  unsigned short* tmp_bf= (unsigned short*)p; p += (size_t)MQ * 256 * 2;   // 10.2 MB
  unsigned short* WvT   = (unsigned short*)p; p += 256 * 256 * 2;
  unsigned short* WoutT = (unsigned short*)p; p += 256 * 256 * 2;
  unsigned short* WqHi  = (unsigned short*)p; p += 384 * 256 * 2;
  unsigned short* WqLo  = (unsigned short*)p; p += 384 * 256 * 2;

  prep_weights<<<dim3(896), dim3(256), 0, stream>>>(
      W_v, W_attn, W_off, W_out, WvT, WoutT, WqHi, WqLo);

  // v = value @ W_v + b_v  (bf16, pair-packed, LDS-coalesced epilogue)
  gemm_mfma<1, unsigned short, true><<<dim3(MV / 128, 2), dim3(256), 0, stream>>>(
      value, WvT, nullptr, b_v, nullptr, v_bf, nullptr, MV, 256);

  // fused q projections: cols 0-255 -> off fp32 (3-term), 256-383 -> attn bf16
  gemm_mfma<3, float><<<dim3((MQ + 127) / 128, 3), dim3(256), 0, stream>>>(
      query, WqHi, WqLo, b_off, b_attn, off_w, att_w, MQ, 384);

  // bilinear sampling + softmax-weighted accumulation (2 waves / query)
  msda_sample7<<<dim3(MQ / 2), dim3(256), 0, stream>>>(
      (const char*)v_bf, off_w, att_w, (ushort4*)tmp_bf);

  // out = tmp @ W_out + b_out
  gemm_mfma<0, float><<<dim3((MQ + 127) / 128, 2), dim3(256), 0, stream>>>(
      tmp_bf, WoutT, nullptr, b_out, nullptr, out, nullptr, MQ, 256);
}

// Round 18
// 120.555 us; speedup vs baseline: 1.0484x; 1.0025x over previous
//
#include <hip/hip_runtime.h>
#include <math.h>

#define B_   2
#define NQ_  10000
#define NV_  21760
#define EMB  256
#define MQ   (B_*NQ_)   // 20000
#define MV   (B_*NV_)   // 43520

typedef short bf16x8 __attribute__((ext_vector_type(8)));
typedef float f32x4  __attribute__((ext_vector_type(4)));

__device__ constexpr int LSc[4] = {0, 16384, 20480, 21504};

__device__ __forceinline__ unsigned short f2bf(float x) {
  unsigned u = __builtin_bit_cast(unsigned, x);
  u += 0x7FFFu + ((u >> 16) & 1u);
  return (unsigned short)(u >> 16);
}
__device__ __forceinline__ float bf2f(unsigned short s) {
  return __builtin_bit_cast(float, (unsigned)s << 16);
}

// ---------------------------------------------------------------------------
// Weight prep v1 (R13 measured-best: 896 tiny blocks; 1.25 MB total,
// L2-absorbed; beats the 28-block "coalesced" v2 by ~5 us [R16]).
// ---------------------------------------------------------------------------
__global__ __launch_bounds__(256) void prep_weights(
    const float* __restrict__ Wv, const float* __restrict__ Wattn,
    const float* __restrict__ Woff, const float* __restrict__ Wout,
    unsigned short* __restrict__ WvT, unsigned short* __restrict__ WoutT,
    unsigned short* __restrict__ WqHi, unsigned short* __restrict__ WqLo) {
  int n = blockIdx.x;       // 0..895
  int k = threadIdx.x;      // 0..255
  if (n < 256) {
    WvT[n * 256 + k] = f2bf(Wv[k * 256 + n]);
  } else if (n < 512) {
    int c = n - 256;
    WoutT[c * 256 + k] = f2bf(Wout[k * 256 + c]);
  } else {
    int qr = n - 512;       // 0..383
    float x = (qr < 256) ? Woff[k * 256 + qr] : Wattn[k * 128 + (qr - 256)];
    unsigned short hi = f2bf(x);
    WqHi[qr * 256 + k] = hi;
    WqLo[qr * 256 + k] = f2bf(x - bf2f(hi));
  }
}

// ---------------------------------------------------------------------------
// MFMA GEMM (R13 form). 128x128 tile, BK=32, 4 waves (2x2), 4x4 frags/wave.
// bf16 staging via global_load_lds(16B): linear LDS dest, pre-swizzled src.
// MODE 0: A bf16, 1-term.   MODE 1: A fp32 (cvt in staging), 1-term.
// MODE 3: A fp32 split hi/lo in staging; 3-term for col0<256 (off cols),
//         1-term for col0>=256 (attn cols, bf16 out via C2).
// VPERM:  v-proj epilogue -> pair-packed bf16 v via LDS + coalesced stores.
// ---------------------------------------------------------------------------
template <int MODE, typename OutT, bool VPERM = false>
__global__ __launch_bounds__(256) void gemm_mfma(
    const void* __restrict__ Aa,
    const unsigned short* __restrict__ Bt, const unsigned short* __restrict__ Bt2,
    const float* __restrict__ bias, const float* __restrict__ bias2,
    OutT* __restrict__ C, unsigned short* __restrict__ C2, int M, int N) {
  constexpr int BM = 128, BK = 32;
  constexpr int SMEM_SHORTS = (MODE == 3 || VPERM) ? 16384 : 8192;
  __shared__ unsigned short smem[SMEM_SHORTS];
  unsigned short* As  = smem;
  unsigned short* Bs  = smem + ((MODE == 3) ? 2 : 1) * BM * BK;
  unsigned short* As2 = smem + BM * BK;       // MODE3 only
  unsigned short* Bs2 = smem + 3 * BM * BK;   // MODE3 only

  const int tid = threadIdx.x;
  const int lane = tid & 63, wv = tid >> 6;
  const int wr = wv >> 1, wc = wv & 1;
  const int row0 = blockIdx.x * BM, col0 = blockIdx.y * BM;

  auto lds_addr = [](int row, int kslot) -> int {
    return row * 64 + ((kslot ^ ((row >> 1) & 3)) << 4);
  };

  auto stage_bf = [&](unsigned short* dst, const unsigned short* src,
                      int rbase, int rmax, int kk) {
#pragma unroll
    for (int i = 0; i < 2; ++i) {
      int idx = tid + 256 * i;
      int row = idx >> 2, ks = idx & 3;
      int rg = min(rbase + row, rmax);
      int xorb = (row >> 1) & 3;
      const unsigned short* gp =
          src + (size_t)rg * 256 + kk + ((ks ^ xorb) << 3);
      unsigned short* lp = dst + (size_t)(wv * 64 + i * 256) * 8;
      __builtin_amdgcn_global_load_lds(
          (const __attribute__((address_space(1))) void*)gp,
          (__attribute__((address_space(3))) void*)lp, 16, 0, 0);
    }
  };
  auto stage_cvt = [&](unsigned short* dst, const float* src,
                       int rbase, int rmax, int kk) {
#pragma unroll
    for (int i = 0; i < 4; ++i) {
      int idx = tid + 256 * i;
      int row = idx >> 3, c4 = idx & 7;
      int rg = min(rbase + row, rmax);
      float4 vdat = *(const float4*)(src + (size_t)rg * 256 + kk + c4 * 4);
      ushort4 o;
      o.x = f2bf(vdat.x); o.y = f2bf(vdat.y);
      o.z = f2bf(vdat.z); o.w = f2bf(vdat.w);
      *(ushort4*)((char*)dst + lds_addr(row, c4 >> 1) + (c4 & 1) * 8) = o;
    }
  };
  auto stage_cvt2 = [&](unsigned short* dstH, unsigned short* dstL,
                        const float* src, int rbase, int rmax, int kk) {
#pragma unroll
    for (int i = 0; i < 4; ++i) {
      int idx = tid + 256 * i;
      int row = idx >> 3, c4 = idx & 7;
      int rg = min(rbase + row, rmax);
      float4 vdat = *(const float4*)(src + (size_t)rg * 256 + kk + c4 * 4);
      ushort4 hh, ll;
      hh.x = f2bf(vdat.x); ll.x = f2bf(vdat.x - bf2f(hh.x));
      hh.y = f2bf(vdat.y); ll.y = f2bf(vdat.y - bf2f(hh.y));
      hh.z = f2bf(vdat.z); ll.z = f2bf(vdat.z - bf2f(hh.z));
      hh.w = f2bf(vdat.w); ll.w = f2bf(vdat.w - bf2f(hh.w));
      int a = lds_addr(row, c4 >> 1) + (c4 & 1) * 8;
      *(ushort4*)((char*)dstH + a) = hh;
      *(ushort4*)((char*)dstL + a) = ll;
    }
  };

  const bool three_term = (MODE == 3) && (col0 < 256);

  f32x4 acc[4][4] = {};

  for (int kk = 0; kk < 256; kk += BK) {
    if (kk) __syncthreads();
    if constexpr (MODE == 1)
      stage_cvt(As, (const float*)Aa, row0, M - 1, kk);
    else if constexpr (MODE == 3) {
      if (three_term)
        stage_cvt2(As, As2, (const float*)Aa, row0, M - 1, kk);
      else
        stage_cvt(As, (const float*)Aa, row0, M - 1, kk);
    } else
      stage_bf(As, (const unsigned short*)Aa, row0, M - 1, kk);
    stage_bf(Bs, Bt, col0, N - 1, kk);
    if constexpr (MODE == 3)
      if (three_term) stage_bf(Bs2, Bt2, col0, N - 1, kk);
    __syncthreads();

    const int kslot = lane >> 4;
    bf16x8 af[4], bfr[4];
#pragma unroll
    for (int i = 0; i < 4; ++i) {
      int ra = wr * 64 + i * 16 + (lane & 15);
      af[i] = *(const bf16x8*)((const char*)As + lds_addr(ra, kslot));
      int rb = wc * 64 + i * 16 + (lane & 15);
      bfr[i] = *(const bf16x8*)((const char*)Bs + lds_addr(rb, kslot));
    }
#pragma unroll
    for (int mi = 0; mi < 4; ++mi)
#pragma unroll
      for (int ni = 0; ni < 4; ++ni)
        acc[mi][ni] = __builtin_amdgcn_mfma_f32_16x16x32_bf16(
            af[mi], bfr[ni], acc[mi][ni], 0, 0, 0);

    if constexpr (MODE == 3) {
      if (three_term) {
        bf16x8 af2[4], bfr2[4];
#pragma unroll
        for (int i = 0; i < 4; ++i) {
          int ra = wr * 64 + i * 16 + (lane & 15);
          af2[i] = *(const bf16x8*)((const char*)As2 + lds_addr(ra, kslot));
          int rb = wc * 64 + i * 16 + (lane & 15);
          bfr2[i] = *(const bf16x8*)((const char*)Bs2 + lds_addr(rb, kslot));
        }
#pragma unroll
        for (int mi = 0; mi < 4; ++mi)
#pragma unroll
          for (int ni = 0; ni < 4; ++ni) {
            acc[mi][ni] = __builtin_amdgcn_mfma_f32_16x16x32_bf16(
                af2[mi], bfr[ni], acc[mi][ni], 0, 0, 0);
            acc[mi][ni] = __builtin_amdgcn_mfma_f32_16x16x32_bf16(
                af[mi], bfr2[ni], acc[mi][ni], 0, 0, 0);
          }
      }
    }
  }

  // epilogue: D frag layout col=lane&15, row=(lane>>4)*4+reg  [m89-verified]
  if constexpr (VPERM) {
    float bb4[4];
#pragma unroll
    for (int ni = 0; ni < 4; ++ni)
      bb4[ni] = bias[col0 + wc * 64 + ni * 16 + (lane & 15)];
    __syncthreads();                 // As/Bs dead; reuse the 32 KB
    unsigned short* pbuf = smem;
#pragma unroll
    for (int mi = 0; mi < 4; ++mi) {
#pragma unroll
      for (int r = 0; r < 4; ++r) {
        int lr = wr * 64 + mi * 16 + ((lane >> 4) << 2) + r;  // local row
        int pb = lr >> 1, par = lr & 1;
#pragma unroll
        for (int ni = 0; ni < 4; ++ni) {
          int lc = wc * 64 + ni * 16 + (lane & 15);
          float val = acc[mi][ni][r] + bb4[ni];
          int hl = lc >> 5, d = lc & 31;
          int off = pb * 512 + hl * 128 + ((d >> 2) << 4) + (par << 3) +
                    ((d & 3) << 1);
          *(unsigned short*)((char*)pbuf + off) = f2bf(val);
        }
      }
    }
    __syncthreads();
    // coalesced write-out: 64 pair-blocks x 512 B (this block's 4 heads)
    int pix0 = row0, bb2 = 0;
    if (pix0 >= NV_) { bb2 = 1; pix0 -= NV_; }
    int lvl = (pix0 >= 16384) + (pix0 >= 20480) + (pix0 >= 21504);
    int rel0 = pix0 - LSc[lvl];
    char* dst = (char*)C + ((size_t)bb2 * NV_ + LSc[lvl]) * 512 +
                (size_t)(rel0 >> 1) * 1024 + (size_t)(col0 >> 5) * 128;
    int pb = tid >> 2, q = tid & 3;
#pragma unroll
    for (int i = 0; i < 8; ++i) {
      int u = q * 16 + i * 64;
      uint4 vd = *(const uint4*)((const char*)pbuf + pb * 512 + u);
      *(uint4*)(dst + (size_t)pb * 1024 + u) = vd;
    }
  } else {
#pragma unroll
    for (int ni = 0; ni < 4; ++ni) {
      int gcol = col0 + wc * 64 + ni * 16 + (lane & 15);
      float bb = (MODE == 3 && gcol >= 256) ? bias2[gcol - 256] : bias[gcol];
#pragma unroll
      for (int mi = 0; mi < 4; ++mi) {
        int rowbase = row0 + wr * 64 + mi * 16 + ((lane >> 4) << 2);
        f32x4 a = acc[mi][ni];
#pragma unroll
        for (int r = 0; r < 4; ++r) {
          int row = rowbase + r;
          if (row < M) {
            float val = a[r] + bb;
            if constexpr (MODE == 3) {
              if (gcol >= 256)
                C2[(size_t)row * 128 + (gcol - 256)] = f2bf(val);  // attn bf16
              else
                ((float*)C)[(size_t)row * 256 + gcol] = val;
            } else if constexpr (sizeof(OutT) == 2) {
              C[(size_t)row * N + gcol] = (OutT)f2bf(val);
            } else {
              C[(size_t)row * N + gcol] = (OutT)val;
            }
          }
        }
      }
    }
  }
}

// ---------------------------------------------------------------------------
// Sampling v7b (R13 measured-best: 53.0 us): 256-thread block = 2 queries x
// 2 waves; wave w owns levels {2w, 2w+1}. Phase 1: one (h,l,p) combo per
// lane (bf16 logits, one 8-B load) -> skewed 32-B LDS slot. Phase 2: 16 x
// 8-B gathers per level (pair-packed bf16 v). Phase 3: LDS wave-pair merge.
// ---------------------------------------------------------------------------
__global__ __launch_bounds__(256) void msda_sample7(
    const char* __restrict__ v,                    // pair-packed bf16
    const float* __restrict__ off,                 // (MQ, 256) fp32
    const unsigned short* __restrict__ attnlg,     // (MQ, 128) bf16
    ushort4* __restrict__ tmp4) {                  // (MQ, 64) bf16 (h,d)
  __shared__ unsigned coeff[2 * 136 * 8];   // 8704 B; first 2 KB reused
  const int tid = threadIdx.x;
  const int lane = tid & 63;
  const int wid = tid >> 6;        // 0..3
  const int wq = wid >> 1;         // query-in-block 0..1
  const int w = wid & 1;           // level-half
  const int bq = blockIdx.x * 2 + wq;
  const int b = (blockIdx.x * 2) / NQ_;   // block-uniform (no straddle)

  unsigned* cbase = coeff + wq * (136 * 8);
  const float* offq = off + (size_t)bq * 256;
  const unsigned short* attq = attnlg + (size_t)bq * 128;

  // ---- phase 1: one combo per lane
  {
    int h = lane >> 3, dl = (lane >> 2) & 1, p = lane & 3;
    int l = 2 * w + dl;
    int Wl = 128 >> l, sh = 7 - l;

    uint2 lg = *(const uint2*)(attq + h * 16 + l * 4);
    float l0 = __builtin_bit_cast(float, lg.x << 16);
    float l1 = __builtin_bit_cast(float, lg.x & 0xFFFF0000u);
    float l2 = __builtin_bit_cast(float, lg.y << 16);
    float l3 = __builtin_bit_cast(float, lg.y & 0xFFFF0000u);
    float m = fmaxf(fmaxf(l0, l1), fmaxf(l2, l3));
    float e0 = expf(l0 - m), e1 = expf(l1 - m);
    float e2 = expf(l2 - m), e3 = expf(l3 - m);
    float ep = (p == 0) ? e0 : (p == 1) ? e1 : (p == 2) ? e2 : e3;
    float wsm = ep / (e0 + e1 + e2 + e3);

    float gx = offq[h * 32 + (l * 4 + p) * 2 + 0];
    float gy = offq[h * 32 + (l * 4 + p) * 2 + 1];
    float s = 0.5f * (float)(Wl - 1);
    float px = fmaf(gx, s, s), py = fmaf(gy, s, s);
    float x0f = floorf(px), y0f = floorf(py);
    float wx = px - x0f, wy = py - y0f;
    int x0 = (int)x0f, y0 = (int)y0f;

    bool bx0 = (unsigned)x0 < (unsigned)Wl, bx1 = (unsigned)(x0 + 1) < (unsigned)Wl;
    bool by0 = (unsigned)y0 < (unsigned)Wl, by1 = (unsigned)(y0 + 1) < (unsigned)Wl;
    int x0c = min(max(x0, 0), Wl - 1), x1c = min(max(x0 + 1, 0), Wl - 1);
    int y0c = min(max(y0, 0), Wl - 1), y1c = min(max(y0 + 1, 0), Wl - 1);

    auto poff = [&](int xx, int yy) -> unsigned {
      return ((unsigned)((yy << (sh - 1)) + (xx >> 1)) << 10) |
             ((unsigned)(xx & 1) << 3);
    };

    float wxm = 1.f - wx, wym = 1.f - wy;
    float w00 = (bx0 & by0) ? wsm * wxm * wym : 0.f;
    float w01 = (bx1 & by0) ? wsm * wx  * wym : 0.f;
    float w10 = (bx0 & by1) ? wsm * wxm * wy  : 0.f;
    float w11 = (bx1 & by1) ? wsm * wx  * wy  : 0.f;

    unsigned* slot = cbase + (h * 17 + l * 4 + p) * 8;
    uint4 s0;
    s0.x = poff(x0c, y0c);
    s0.y = poff(x1c, y0c);
    s0.z = poff(x0c, y1c);
    s0.w = poff(x1c, y1c);
    *(uint4*)slot = s0;
    uint4 s1;
    s1.x = __builtin_bit_cast(unsigned, w00);
    s1.y = __builtin_bit_cast(unsigned, w01);
    s1.z = __builtin_bit_cast(unsigned, w10);
    s1.w = __builtin_bit_cast(unsigned, w11);
    *(uint4*)(slot + 4) = s1;
  }
  __syncthreads();

  // ---- phase 2: this wave's two levels
  const int h = lane >> 3, c4 = lane & 7;
  const unsigned laneoff = (unsigned)(h * 128 + c4 * 16);
  float4 acc = make_float4(0.f, 0.f, 0.f, 0.f);

#pragma unroll
  for (int dl = 0; dl < 2; ++dl) {
    const int l = 2 * w + dl;
    const char* lb = v + ((size_t)b * NV_ + LSc[l]) * 512;
    const unsigned* cb = cbase + (h * 17 + l * 4) * 8;
#pragma unroll
    for (int p = 0; p < 4; ++p) {
      uint4 s0 = *(const uint4*)(cb + p * 8);
      uint4 s1 = *(const uint4*)(cb + p * 8 + 4);
      float w00 = __builtin_bit_cast(float, s1.x);
      float w01 = __builtin_bit_cast(float, s1.y);
      float w10 = __builtin_bit_cast(float, s1.z);
      float w11 = __builtin_bit_cast(float, s1.w);

      uint2 r00 = *(const uint2*)(lb + (laneoff + s0.x));
      uint2 r01 = *(const uint2*)(lb + (laneoff + s0.y));
      uint2 r10 = *(const uint2*)(lb + (laneoff + s0.z));
      uint2 r11 = *(const uint2*)(lb + (laneoff + s0.w));

      acc.x += w00 * __builtin_bit_cast(float, r00.x << 16)
             + w01 * __builtin_bit_cast(float, r01.x << 16)
             + w10 * __builtin_bit_cast(float, r10.x << 16)
             + w11 * __builtin_bit_cast(float, r11.x << 16);
      acc.y += w00 * __builtin_bit_cast(float, r00.x & 0xFFFF0000u)
             + w01 * __builtin_bit_cast(float, r01.x & 0xFFFF0000u)
             + w10 * __builtin_bit_cast(float, r10.x & 0xFFFF0000u)
             + w11 * __builtin_bit_cast(float, r11.x & 0xFFFF0000u);
      acc.z += w00 * __builtin_bit_cast(float, r00.y << 16)
             + w01 * __builtin_bit_cast(float, r01.y << 16)
             + w10 * __builtin_bit_cast(float, r10.y << 16)
             + w11 * __builtin_bit_cast(float, r11.y << 16);
      acc.w += w00 * __builtin_bit_cast(float, r00.y & 0xFFFF0000u)
             + w01 * __builtin_bit_cast(float, r01.y & 0xFFFF0000u)
             + w10 * __builtin_bit_cast(float, r10.y & 0xFFFF0000u)
             + w11 * __builtin_bit_cast(float, r11.y & 0xFFFF0000u);
    }
  }

  // ---- phase 3: merge wave pairs via LDS (coeff dead after barrier)
  __syncthreads();
  float4* red = (float4*)coeff;    // 2 q x 64 lanes x 16 B = 2048 B
  if (w == 1) red[wq * 64 + lane] = acc;
  __syncthreads();
  if (w == 0) {
    float4 o2 = red[wq * 64 + lane];
    acc.x += o2.x; acc.y += o2.y; acc.z += o2.z; acc.w += o2.w;
    ushort4 o;
    o.x = f2bf(acc.x); o.y = f2bf(acc.y); o.z = f2bf(acc.z); o.w = f2bf(acc.w);
    tmp4[(size_t)bq * 64 + lane] = o;
  }
}

// ---------------------------------------------------------------------------
extern "C" void kernel_launch(void* const* d_in, const int* in_sizes, int n_in,
                              void* d_out, int out_size, void* d_ws, size_t ws_size,
                              hipStream_t stream) {
  const float* query  = (const float*)d_in[0];
  // d_in[1] = key (unused)
  const float* value  = (const float*)d_in[2];
  const float* W_off  = (const float*)d_in[3];
  const float* b_off  = (const float*)d_in[4];
  const float* W_attn = (const float*)d_in[5];
  const float* b_attn = (const float*)d_in[6];
  const float* W_v    = (const float*)d_in[7];
  const float* b_v    = (const float*)d_in[8];
  const float* W_out  = (const float*)d_in[9];
  const float* b_out  = (const float*)d_in[10];
  float* out = (float*)d_out;

  char* p = (char*)d_ws;
  unsigned short* v_bf  = (unsigned short*)p; p += (size_t)MV * 256 * 2;   // 22.3 MB
  float*          off_w = (float*)p;          p += (size_t)MQ * 256 * 4;   // 20.5 MB
  unsigned short* att_w = (unsigned short*)p; p += (size_t)MQ * 128 * 2;   //  5.1 MB
  unsigned short* tmp_bf= (unsigned short*)p; p += (size_t)MQ * 256 * 2;   // 10.2 MB
  unsigned short* WvT   = (unsigned short*)p; p += 256 * 256 * 2;
  unsigned short* WoutT = (unsigned short*)p; p += 256 * 256 * 2;
  unsigned short* WqHi  = (unsigned short*)p; p += 384 * 256 * 2;
  unsigned short* WqLo  = (unsigned short*)p; p += 384 * 256 * 2;

  prep_weights<<<dim3(896), dim3(256), 0, stream>>>(
      W_v, W_attn, W_off, W_out, WvT, WoutT, WqHi, WqLo);

  // v = value @ W_v + b_v  (bf16, pair-packed, LDS-coalesced epilogue)
  gemm_mfma<1, unsigned short, true><<<dim3(MV / 128, 2), dim3(256), 0, stream>>>(
      value, WvT, nullptr, b_v, nullptr, v_bf, nullptr, MV, 256);

  // fused q projections: cols 0-255 -> off fp32 (3-term), 256-383 -> attn bf16
  gemm_mfma<3, float><<<dim3((MQ + 127) / 128, 3), dim3(256), 0, stream>>>(
      query, WqHi, WqLo, b_off, b_attn, off_w, att_w, MQ, 384);

  // bilinear sampling + softmax-weighted accumulation (2 waves / query)
  msda_sample7<<<dim3(MQ / 2), dim3(256), 0, stream>>>(
      (const char*)v_bf, off_w, att_w, (ushort4*)tmp_bf);

  // out = tmp @ W_out + b_out
  gemm_mfma<0, float><<<dim3((MQ + 127) / 128, 2), dim3(256), 0, stream>>>(
      tmp_bf, WoutT, nullptr, b_out, nullptr, out, nullptr, MQ, 256);
}